// Round 3
// baseline (388.885 us; speedup 1.0000x reference)
//
#include <hip/hip_runtime.h>
#include <math.h>
#include <stdint.h>

#define B_ 64
#define J_ 512
#define D_ 1024

typedef __attribute__((ext_vector_type(8))) short short8;
typedef __attribute__((ext_vector_type(4))) float f32x4;

#define GLOBAL_AS __attribute__((address_space(1)))
#define LDS_AS    __attribute__((address_space(3)))

__device__ __forceinline__ void async16(const void* g, void* l) {
    __builtin_amdgcn_global_load_lds((const GLOBAL_AS uint32_t*)g,
                                     (LDS_AS uint32_t*)l, 16, 0, 0);
}

// tanh(x) = 1 - 2/(1+e^{2x}); saturates correctly for |x| large.
__device__ __forceinline__ float fast_tanh(float x) {
    return 1.0f - 2.0f / (1.0f + __expf(2.0f * x));
}

// fp32 -> bf16 round-to-nearest-even
__device__ __forceinline__ uint32_t f2bf(float f) {
    uint32_t u = __builtin_bit_cast(uint32_t, f);
    u += 0x7fffu + ((u >> 16) & 1u);
    return u >> 16;
}
__device__ __forceinline__ uint32_t pack2(float lo, float hi) {
    return f2bf(lo) | (f2bf(hi) << 16);
}

// W1[k][n] fp32 -> W1t[n][k] bf16 (so B-operand frags are contiguous in k)
__global__ __launch_bounds__(256) void transpose_cast_w1(const float* __restrict__ W1,
                                                         unsigned short* __restrict__ W1t) {
    __shared__ float t[32][33];
    const int n = blockIdx.x * 32 + threadIdx.x;
    for (int i = threadIdx.y; i < 32; i += 8)
        t[i][threadIdx.x] = W1[(size_t)(blockIdx.y * 32 + i) * D_ + n];
    __syncthreads();
    const int k = blockIdx.y * 32 + threadIdx.x;
    for (int i = threadIdx.y; i < 32; i += 8)
        W1t[(size_t)(blockIdx.x * 32 + i) * D_ + k] =
            (unsigned short)f2bf(t[threadIdx.x][i]);
}

// Block tile: 64(M) x 512(N-chunk), BK=64, 8 waves each 64x64 (16 MFMA : 8 ds_read).
// A is cast fp32->bf16 in-register during staging (no separate cast pass).
// Fused tanh/W2 fold, sigmoid/mask, and per-block unnormalized pooling partials
// (normalization commutes to finalize; no atomics, no memset).
__global__ __launch_bounds__(512, 4) void gemm_score_kernel(
    const float* __restrict__ x, const unsigned short* __restrict__ W1t,
    const float* __restrict__ b1, const float* __restrict__ W2,
    const float* __restrict__ b2, const float* __restrict__ mask,
    float* __restrict__ val_ws, float* __restrict__ pooled_part)
{
    __shared__ __align__(16) unsigned short ldsA[64 * 64];    // [m][k], k-chunk swizzled
    __shared__ __align__(16) unsigned short ldsB[512 * 64];   // [n][k], k-chunk swizzled
    __shared__ float pv_part[8][64];
    __shared__ float vrow[64];

    const int tid  = threadIdx.x;
    const int wave = tid >> 6;
    const int l    = tid & 63;
    const int wn   = wave;            // wave grid 1(M) x 8(N)
    const int l15  = l & 15;
    const int kgrp = l >> 4;
    const int r0   = blockIdx.x * 64; // 64 rows per block, within one batch

    // --- A staging: thread loads 8 fp32, packs to bf16, ds_write_b128 swizzled ---
    const int am = tid >> 3;                 // row 0..63
    const int ac = tid & 7;                  // logical k-chunk 0..7
    const int aphys = ac ^ (am & 7);         // swizzled placement
    const float* gA = x + (size_t)(r0 + am) * D_ + (ac << 3);
    uint4* ldsA_w = reinterpret_cast<uint4*>(ldsA + am * 64 + (aphys << 3));

    // --- B staging via global_load_lds (global address carries the swizzle) ---
    const unsigned short* gB[8];
    unsigned short* lB[8];
    #pragma unroll
    for (int t = 0; t < 8; ++t) {
        const int f   = tid + t * 512;       // 0..4095
        const int row = f >> 3;              // 0..511
        const int ch  = ((f & 7) ^ (row & 7)) << 3;
        gB[t] = W1t + (size_t)row * D_ + ch;
        lB[t] = ldsB + t * 4096 + (wave << 9);
    }

    // --- fragment LDS offsets (ushort units), swizzle-consistent ---
    int aoff[4][2], boff[4][2];
    #pragma unroll
    for (int mi = 0; mi < 4; ++mi)
        #pragma unroll
        for (int ks = 0; ks < 2; ++ks)
            aoff[mi][ks] = (mi * 16 + l15) * 64 +
                           (((ks * 4 + kgrp) ^ ((mi * 16 + l15) & 7)) << 3);
    #pragma unroll
    for (int ni = 0; ni < 4; ++ni)
        #pragma unroll
        for (int ks = 0; ks < 2; ++ks) {
            const int row = wn * 64 + ni * 16 + l15;
            boff[ni][ks] = row * 64 + (((ks * 4 + kgrp) ^ (row & 7)) << 3);
        }

    float pv[4][4];
    #pragma unroll
    for (int mi = 0; mi < 4; ++mi)
        #pragma unroll
        for (int r = 0; r < 4; ++r) pv[mi][r] = 0.f;

    for (int n0 = 0; n0 < 2; ++n0) {
        f32x4 acc[4][4];
        #pragma unroll
        for (int mi = 0; mi < 4; ++mi)
            #pragma unroll
            for (int ni = 0; ni < 4; ++ni)
                acc[mi][ni] = (f32x4){0.f, 0.f, 0.f, 0.f};

        const size_t bofs = (size_t)n0 * 512 * D_;
        for (int k0 = 0; k0 < D_; k0 += 64) {
            // A: fp32 -> bf16 in-register
            const float4 xa0 = *reinterpret_cast<const float4*>(gA + k0);
            const float4 xa1 = *reinterpret_cast<const float4*>(gA + k0 + 4);
            uint4 pk;
            pk.x = pack2(xa0.x, xa0.y);
            pk.y = pack2(xa0.z, xa0.w);
            pk.z = pack2(xa1.x, xa1.y);
            pk.w = pack2(xa1.z, xa1.w);
            *ldsA_w = pk;
            // B: async direct-to-LDS
            #pragma unroll
            for (int t = 0; t < 8; ++t) async16(gB[t] + bofs + k0, lB[t]);
            __syncthreads();

            #pragma unroll
            for (int ks = 0; ks < 2; ++ks) {
                const short8 a0 = *reinterpret_cast<const short8*>(ldsA + aoff[0][ks]);
                const short8 a1 = *reinterpret_cast<const short8*>(ldsA + aoff[1][ks]);
                const short8 a2 = *reinterpret_cast<const short8*>(ldsA + aoff[2][ks]);
                const short8 a3 = *reinterpret_cast<const short8*>(ldsA + aoff[3][ks]);
                const short8 b0 = *reinterpret_cast<const short8*>(ldsB + boff[0][ks]);
                const short8 b1f = *reinterpret_cast<const short8*>(ldsB + boff[1][ks]);
                const short8 b2f = *reinterpret_cast<const short8*>(ldsB + boff[2][ks]);
                const short8 b3f = *reinterpret_cast<const short8*>(ldsB + boff[3][ks]);
                #pragma unroll
                for (int mi = 0; mi < 4; ++mi) {
                    const short8 a = (mi == 0) ? a0 : (mi == 1) ? a1 : (mi == 2) ? a2 : a3;
                    acc[mi][0] = __builtin_amdgcn_mfma_f32_16x16x32_bf16(a, b0,  acc[mi][0], 0, 0, 0);
                    acc[mi][1] = __builtin_amdgcn_mfma_f32_16x16x32_bf16(a, b1f, acc[mi][1], 0, 0, 0);
                    acc[mi][2] = __builtin_amdgcn_mfma_f32_16x16x32_bf16(a, b2f, acc[mi][2], 0, 0, 0);
                    acc[mi][3] = __builtin_amdgcn_mfma_f32_16x16x32_bf16(a, b3f, acc[mi][3], 0, 0, 0);
                }
            }
            __syncthreads();
        }

        // fold this 512-col n-chunk of h into pv (h never materialized)
        #pragma unroll
        for (int ni = 0; ni < 4; ++ni) {
            const int col = n0 * 512 + wn * 64 + ni * 16 + l15;
            const float b1v = b1[col];
            const float w2v = W2[col];
            #pragma unroll
            for (int mi = 0; mi < 4; ++mi)
                #pragma unroll
                for (int r = 0; r < 4; ++r) {
                    const float h = fast_tanh(acc[mi][ni][r] + b1v);
                    pv[mi][r] = fmaf(h, w2v, pv[mi][r]);
                }
        }
    }

    // reduce pv over the 16 col-lanes (C/D layout: row = kgrp*4+r, col = l15)
    #pragma unroll
    for (int mi = 0; mi < 4; ++mi)
        #pragma unroll
        for (int r = 0; r < 4; ++r) {
            float s = pv[mi][r];
            s += __shfl_xor(s, 1);
            s += __shfl_xor(s, 2);
            s += __shfl_xor(s, 4);
            s += __shfl_xor(s, 8);
            if (l15 == 0) pv_part[wn][mi * 16 + kgrp * 4 + r] = s;
        }
    __syncthreads();
    if (tid < 64) {
        float s = b2[0];
        #pragma unroll
        for (int w = 0; w < 8; ++w) s += pv_part[w][tid];
        const float sg = 1.0f / (1.0f + __expf(-s));
        const float v = sg * mask[r0 + tid];
        val_ws[r0 + tid] = v;
        vrow[tid] = v;
    }
    __syncthreads();

    // per-block unnormalized pooled partial: pooled_part[blk][k] = sum_rows x[r][k]*val[r]
    const int kc = tid << 1;
    float a0 = 0.f, a1 = 0.f;
    for (int row = 0; row < 64; ++row) {
        const float v = vrow[row];
        const float2 xv = *reinterpret_cast<const float2*>(
            x + (size_t)(r0 + row) * D_ + kc);
        a0 = fmaf(xv.x, v, a0);
        a1 = fmaf(xv.y, v, a1);
    }
    float2* pp = reinterpret_cast<float2*>(pooled_part + (size_t)blockIdx.x * D_ + kc);
    *pp = make_float2(a0, a1);
}

__global__ __launch_bounds__(256) void finalize_kernel(
    const float* __restrict__ val_ws, const float* __restrict__ pooled_part,
    const float* __restrict__ W3, const float* __restrict__ b3,
    float* __restrict__ out)
{
    __shared__ float sred[256];
    const int b = blockIdx.x;
    const int tid = threadIdx.x;

    const float v0 = val_ws[b * J_ + tid];
    const float v1 = val_ws[b * J_ + 256 + tid];
    sred[tid] = v0 + v1;
    __syncthreads();
    for (int s = 128; s > 0; s >>= 1) {
        if (tid < s) sred[tid] += sred[tid + s];
        __syncthreads();
    }
    const float inv = 1.0f / sred[0];

    out[192 + b * J_ + tid]       = v0 * inv;
    out[192 + b * J_ + 256 + tid] = v1 * inv;

    // sum the 8 per-block pooled partials for this batch, normalize, apply W3
    const int k = tid << 2;
    float acc3[3] = {0.f, 0.f, 0.f};
    #pragma unroll
    for (int c = 0; c < 4; ++c) {
        float p = 0.f;
        #pragma unroll
        for (int i = 0; i < 8; ++i)
            p += pooled_part[(size_t)(b * 8 + i) * D_ + k + c];
        p *= inv;
        acc3[0] = fmaf(p, W3[(k + c) * 3 + 0], acc3[0]);
        acc3[1] = fmaf(p, W3[(k + c) * 3 + 1], acc3[1]);
        acc3[2] = fmaf(p, W3[(k + c) * 3 + 2], acc3[2]);
    }
    for (int o = 0; o < 3; ++o) {
        __syncthreads();
        sred[tid] = acc3[o];
        __syncthreads();
        for (int s = 128; s > 0; s >>= 1) {
            if (tid < s) sred[tid] += sred[tid + s];
            __syncthreads();
        }
        if (tid == 0) out[b * 3 + o] = sred[0] + b3[o];
    }
}

extern "C" void kernel_launch(void* const* d_in, const int* in_sizes, int n_in,
                              void* d_out, int out_size, void* d_ws, size_t ws_size,
                              hipStream_t stream) {
    const float* x    = (const float*)d_in[0];
    const float* mask = (const float*)d_in[1];
    const float* W1   = (const float*)d_in[2];
    const float* b1   = (const float*)d_in[3];
    const float* W2   = (const float*)d_in[4];
    const float* b2   = (const float*)d_in[5];
    const float* W3   = (const float*)d_in[6];
    const float* b3   = (const float*)d_in[7];
    float* out = (float*)d_out;

    const size_t W1T_BYTES  = (size_t)D_ * D_ * 2;        // 2 MB
    const size_t VAL_BYTES  = (size_t)B_ * J_ * 4;        // 128 KB
    // pooled partials: 512 blocks x D floats = 2 MB

    unsigned short* W1t = (unsigned short*)d_ws;
    float* val_ws       = (float*)((char*)d_ws + W1T_BYTES);
    float* pooled_part  = (float*)((char*)d_ws + W1T_BYTES + VAL_BYTES);

    transpose_cast_w1<<<dim3(32, 32), dim3(32, 8), 0, stream>>>(W1, W1t);
    gemm_score_kernel<<<512, 512, 0, stream>>>(x, W1t, b1, W2, b2, mask,
                                               val_ws, pooled_part);
    finalize_kernel<<<B_, 256, 0, stream>>>(val_ws, pooled_part, W3, b3, out);
}

// Round 5
// 321.121 us; speedup vs baseline: 1.2110x; 1.2110x over previous
//
#include <hip/hip_runtime.h>
#include <math.h>
#include <stdint.h>

#define B_ 64
#define J_ 512
#define D_ 1024

typedef __attribute__((ext_vector_type(8))) short short8;
typedef __attribute__((ext_vector_type(4))) float f32x4;

#define GLOBAL_AS __attribute__((address_space(1)))
#define LDS_AS    __attribute__((address_space(3)))

__device__ __forceinline__ void async16(const void* g, void* l) {
    __builtin_amdgcn_global_load_lds((const GLOBAL_AS uint32_t*)g,
                                     (LDS_AS uint32_t*)l, 16, 0, 0);
}

// tanh(x) = 1 - 2/(1+e^{2x}); saturates correctly for |x| large.
__device__ __forceinline__ float fast_tanh(float x) {
    return 1.0f - 2.0f / (1.0f + __expf(2.0f * x));
}

// fp32 -> bf16 round-to-nearest-even
__device__ __forceinline__ uint32_t f2bf(float f) {
    uint32_t u = __builtin_bit_cast(uint32_t, f);
    u += 0x7fffu + ((u >> 16) & 1u);
    return u >> 16;
}
__device__ __forceinline__ uint32_t pack2(float lo, float hi) {
    return f2bf(lo) | (f2bf(hi) << 16);
}

// W1[k][n] fp32 -> W1t[n][k] bf16 (so B-operand frags are contiguous in k)
// (validated rounds 2-3)
__global__ __launch_bounds__(256) void transpose_cast_w1(const float* __restrict__ W1,
                                                         unsigned short* __restrict__ W1t) {
    __shared__ float t[32][33];
    const int n = blockIdx.x * 32 + threadIdx.x;
    for (int i = threadIdx.y; i < 32; i += 8)
        t[i][threadIdx.x] = W1[(size_t)(blockIdx.y * 32 + i) * D_ + n];
    __syncthreads();
    const int k = blockIdx.y * 32 + threadIdx.x;
    for (int i = threadIdx.y; i < 32; i += 8)
        W1t[(size_t)(blockIdx.x * 32 + i) * D_ + k] =
            (unsigned short)f2bf(t[threadIdx.x][i]);
}

// Block tile: 64(M) x 256(N-chunk) x 4 sweeps, BK=64. 4 waves, wave tile 64x64
// (32 MFMA : 16 ds_read_b128 per k-step -> at the LDS/MFMA balance point).
// A cast fp32->bf16 in-register during staging; B async global->LDS.
// launch_bounds(256,2): 256-reg budget, no spill (round-3 failure mode), 2 blk/CU.
__global__ __launch_bounds__(256, 2) void gemm_score_kernel(
    const float* __restrict__ x, const unsigned short* __restrict__ W1t,
    const float* __restrict__ b1, const float* __restrict__ W2,
    const float* __restrict__ b2, const float* __restrict__ mask,
    float* __restrict__ val_ws, float* __restrict__ pooled_part)
{
    __shared__ __align__(16) unsigned short ldsA[64 * 64];    // [m][k], swizzled chunks
    __shared__ __align__(16) unsigned short ldsB[256 * 64];   // [n][k], swizzled chunks
    __shared__ float pv_part[4][64];
    __shared__ float vrow[64];

    const int tid  = threadIdx.x;
    const int wave = tid >> 6;
    const int l    = tid & 63;
    const int l15  = l & 15;
    const int kgrp = l >> 4;
    const int l7   = l & 7;
    const int r0   = blockIdx.x * 64;   // rows of this block (within one batch)

    // A staging: thread loads 8 fp32 from 2 rows, packs bf16, swizzled ds_write_b128
    const int ar = tid >> 3;            // 0..31
    const int ac = tid & 7;             // logical k-chunk
    const float* gA0 = x + (size_t)(r0 + ar) * D_ + (ac << 3);
    const float* gA1 = gA0 + (size_t)32 * D_;
    uint4* dA0 = (uint4*)(ldsA + ar * 64 + ((ac ^ (ar & 7)) << 3));
    uint4* dA1 = (uint4*)(ldsA + (ar + 32) * 64 + ((ac ^ (ar & 7)) << 3));

    // B staging via global_load_lds (lds dest = wave base + lane*16; the global
    // address carries the swizzle): row = t*32 + wave*8 + (l>>3), phys chunk =
    // l&7, logical = phys ^ (row&7) with row&7 == l>>3.
    const int brl  = l >> 3;
    const int blog = (l & 7) ^ brl;
    size_t gBoff[8];
    unsigned short* lB[8];
    #pragma unroll
    for (int t = 0; t < 8; ++t) {
        const int row = t * 32 + wave * 8 + brl;
        gBoff[t] = (size_t)row * D_ + (blog << 3);
        lB[t] = ldsB + t * 2048 + wave * 512;
    }

    // fragment LDS offsets (ushort units), swizzle-consistent (validated r2)
    int aoff[4][2], boff[4][2];
    #pragma unroll
    for (int mi = 0; mi < 4; ++mi)
        #pragma unroll
        for (int ks = 0; ks < 2; ++ks)
            aoff[mi][ks] = (mi * 16 + l15) * 64 + (((ks * 4 + kgrp) ^ l7) << 3);
    #pragma unroll
    for (int ni = 0; ni < 4; ++ni)
        #pragma unroll
        for (int ks = 0; ks < 2; ++ks) {
            const int row = wave * 64 + ni * 16 + l15;
            boff[ni][ks] = row * 64 + (((ks * 4 + kgrp) ^ l7) << 3);
        }

    float pv[4][4];
    #pragma unroll
    for (int mi = 0; mi < 4; ++mi)
        #pragma unroll
        for (int r = 0; r < 4; ++r) pv[mi][r] = 0.f;

    for (int n0 = 0; n0 < 4; ++n0) {
        f32x4 acc[4][4];
        #pragma unroll
        for (int mi = 0; mi < 4; ++mi)
            #pragma unroll
            for (int ni = 0; ni < 4; ++ni)
                acc[mi][ni] = (f32x4){0.f, 0.f, 0.f, 0.f};

        const size_t nofs = (size_t)n0 * 256 * D_;
        for (int k0 = 0; k0 < D_; k0 += 64) {
            const float4 a00 = *reinterpret_cast<const float4*>(gA0 + k0);
            const float4 a01 = *reinterpret_cast<const float4*>(gA0 + k0 + 4);
            const float4 a10 = *reinterpret_cast<const float4*>(gA1 + k0);
            const float4 a11 = *reinterpret_cast<const float4*>(gA1 + k0 + 4);
            uint4 p0, p1;
            p0.x = pack2(a00.x, a00.y); p0.y = pack2(a00.z, a00.w);
            p0.z = pack2(a01.x, a01.y); p0.w = pack2(a01.z, a01.w);
            p1.x = pack2(a10.x, a10.y); p1.y = pack2(a10.z, a10.w);
            p1.z = pack2(a11.x, a11.y); p1.w = pack2(a11.z, a11.w);
            *dA0 = p0;
            *dA1 = p1;
            #pragma unroll
            for (int t = 0; t < 8; ++t)
                async16(W1t + nofs + gBoff[t] + k0, lB[t]);
            __syncthreads();

            #pragma unroll
            for (int ks = 0; ks < 2; ++ks) {
                short8 af[4], bfr[4];
                #pragma unroll
                for (int mi = 0; mi < 4; ++mi)
                    af[mi] = *reinterpret_cast<const short8*>(ldsA + aoff[mi][ks]);
                #pragma unroll
                for (int ni = 0; ni < 4; ++ni)
                    bfr[ni] = *reinterpret_cast<const short8*>(ldsB + boff[ni][ks]);
                #pragma unroll
                for (int mi = 0; mi < 4; ++mi)
                    #pragma unroll
                    for (int ni = 0; ni < 4; ++ni)
                        acc[mi][ni] = __builtin_amdgcn_mfma_f32_16x16x32_bf16(
                            af[mi], bfr[ni], acc[mi][ni], 0, 0, 0);
            }
            __syncthreads();
        }

        // fold this 256-col n-chunk of h into pv (h never materialized)
        #pragma unroll
        for (int ni = 0; ni < 4; ++ni) {
            const int col = n0 * 256 + wave * 64 + ni * 16 + l15;
            const float b1v = b1[col];
            const float w2v = W2[col];
            #pragma unroll
            for (int mi = 0; mi < 4; ++mi)
                #pragma unroll
                for (int r = 0; r < 4; ++r) {
                    const float h = fast_tanh(acc[mi][ni][r] + b1v);
                    pv[mi][r] = fmaf(h, w2v, pv[mi][r]);
                }
        }
    }

    // reduce pv over the 16 col-lanes (C/D layout: row = kgrp*4+r, col = l15)
    #pragma unroll
    for (int mi = 0; mi < 4; ++mi)
        #pragma unroll
        for (int r = 0; r < 4; ++r) {
            float s = pv[mi][r];
            s += __shfl_xor(s, 1);
            s += __shfl_xor(s, 2);
            s += __shfl_xor(s, 4);
            s += __shfl_xor(s, 8);
            if (l15 == 0) pv_part[wave][mi * 16 + kgrp * 4 + r] = s;
        }
    __syncthreads();
    if (tid < 64) {
        float s = b2[0];
        #pragma unroll
        for (int w = 0; w < 4; ++w) s += pv_part[w][tid];
        const float sg = 1.0f / (1.0f + __expf(-s));
        const float v = sg * mask[r0 + tid];
        val_ws[r0 + tid] = v;
        vrow[tid] = v;
    }
    __syncthreads();

    // unnormalized pooled partial for this block (normalization commutes)
    {
        const int kc = tid << 2;
        float a0 = 0.f, a1 = 0.f, a2 = 0.f, a3 = 0.f;
        for (int row = 0; row < 64; ++row) {
            const float v = vrow[row];
            const float4 xv = *reinterpret_cast<const float4*>(
                x + (size_t)(r0 + row) * D_ + kc);
            a0 = fmaf(xv.x, v, a0);
            a1 = fmaf(xv.y, v, a1);
            a2 = fmaf(xv.z, v, a2);
            a3 = fmaf(xv.w, v, a3);
        }
        *reinterpret_cast<float4*>(pooled_part + (size_t)blockIdx.x * D_ + kc) =
            make_float4(a0, a1, a2, a3);
    }
}

__global__ __launch_bounds__(256) void finalize_kernel(
    const float* __restrict__ val_ws, const float* __restrict__ pooled_part,
    const float* __restrict__ W3, const float* __restrict__ b3,
    float* __restrict__ out)
{
    __shared__ float sred[256];
    const int b = blockIdx.x;
    const int tid = threadIdx.x;

    const float v0 = val_ws[b * J_ + tid];
    const float v1 = val_ws[b * J_ + 256 + tid];
    sred[tid] = v0 + v1;
    __syncthreads();
    for (int s = 128; s > 0; s >>= 1) {
        if (tid < s) sred[tid] += sred[tid + s];
        __syncthreads();
    }
    const float inv = 1.0f / sred[0];

    out[192 + b * J_ + tid]       = v0 * inv;
    out[192 + b * J_ + 256 + tid] = v1 * inv;

    // sum the 8 per-block pooled partials for this batch, normalize, apply W3
    const int k = tid << 2;
    float acc3[3] = {0.f, 0.f, 0.f};
    #pragma unroll
    for (int c = 0; c < 4; ++c) {
        float p = 0.f;
        #pragma unroll
        for (int i = 0; i < 8; ++i)
            p += pooled_part[(size_t)(b * 8 + i) * D_ + k + c];
        p *= inv;
        acc3[0] = fmaf(p, W3[(k + c) * 3 + 0], acc3[0]);
        acc3[1] = fmaf(p, W3[(k + c) * 3 + 1], acc3[1]);
        acc3[2] = fmaf(p, W3[(k + c) * 3 + 2], acc3[2]);
    }
    for (int o = 0; o < 3; ++o) {
        __syncthreads();
        sred[tid] = acc3[o];
        __syncthreads();
        for (int s = 128; s > 0; s >>= 1) {
            if (tid < s) sred[tid] += sred[tid + s];
            __syncthreads();
        }
        if (tid == 0) out[b * 3 + o] = sred[0] + b3[o];
    }
}

extern "C" void kernel_launch(void* const* d_in, const int* in_sizes, int n_in,
                              void* d_out, int out_size, void* d_ws, size_t ws_size,
                              hipStream_t stream) {
    const float* x    = (const float*)d_in[0];
    const float* mask = (const float*)d_in[1];
    const float* W1   = (const float*)d_in[2];
    const float* b1   = (const float*)d_in[3];
    const float* W2   = (const float*)d_in[4];
    const float* b2   = (const float*)d_in[5];
    const float* W3   = (const float*)d_in[6];
    const float* b3   = (const float*)d_in[7];
    float* out = (float*)d_out;

    unsigned short* W1t = (unsigned short*)d_ws;                       // 2 MB
    float* val_ws       = (float*)((char*)d_ws + 2097152);             // 128 KB
    float* pooled_part  = (float*)((char*)d_ws + 2097152 + 131072);    // 2 MB

    transpose_cast_w1<<<dim3(32, 32), dim3(32, 8), 0, stream>>>(W1, W1t);
    gemm_score_kernel<<<512, 256, 0, stream>>>(x, W1t, b1, W2, b2, mask,
                                               val_ws, pooled_part);
    finalize_kernel<<<B_, 256, 0, stream>>>(val_ws, pooled_part, W3, b3, out);
}